// Round 1
// baseline (142.655 us; speedup 1.0000x reference)
//
#include <hip/hip_runtime.h>

#define KW 11
#define IMG_H 512
#define IMG_W 512
#define OUT_H 502
#define OUT_W 502
#define TILE 32
#define HALO (KW - 1)          // 10
#define STAGE (TILE + HALO)    // 42
#define SPITCH 44              // staging pitch (pad from 42)
#define NPLANE 48              // B*C = 16*3
#define C1 0.0001f
#define C2 0.0004f

// One block = one 32x32 output tile of one (b,c) plane.
// grid = (16, 16, 48); block = 256.
__global__ __launch_bounds__(256) void ssim_tile(
    const float* __restrict__ in, const float* __restrict__ tgt,
    const float* __restrict__ w, float* __restrict__ partial)
{
    __shared__ float sx[STAGE][SPITCH];
    __shared__ float sy[STAGE][SPITCH];
    __shared__ float hx[STAGE][TILE];
    __shared__ float hy[STAGE][TILE];
    __shared__ float hxx[STAGE][TILE];
    __shared__ float hyy[STAGE][TILE];
    __shared__ float hxy[STAGE][TILE];
    __shared__ float g1s[KW];
    __shared__ float red[4];

    const int tid = threadIdx.x;
    const int gx0 = blockIdx.x * TILE;
    const int gy0 = blockIdx.y * TILE;
    const float* ip = in  + (size_t)blockIdx.z * (IMG_H * IMG_W);
    const float* tp = tgt + (size_t)blockIdx.z * (IMG_H * IMG_W);

    // Recover the exact normalized 1D factor: row sums of the 2D kernel
    // (w2d[i][j] = g1[i]*g1[j], sum g1 = 1  ->  row_sum[i] = g1[i]).
    if (tid < KW) {
        float s = 0.f;
        #pragma unroll
        for (int j = 0; j < KW; ++j) s += w[tid * KW + j];
        g1s[tid] = s;
    }

    // Stage input/target tile (42x42, zero-fill OOB; OOB outputs are masked).
    for (int s = tid; s < STAGE * STAGE; s += 256) {
        int r = s / STAGE, c = s % STAGE;
        int gy = gy0 + r, gx = gx0 + c;
        float xv = 0.f, yv = 0.f;
        if (gy < IMG_H && gx < IMG_W) {
            xv = ip[gy * IMG_W + gx];
            yv = tp[gy * IMG_W + gx];
        }
        sx[r][c] = xv;
        sy[r][c] = yv;
    }
    __syncthreads();

    float g[KW];
    #pragma unroll
    for (int j = 0; j < KW; ++j) g[j] = g1s[j];  // LDS broadcast, free

    // Horizontal separable pass: 42 rows x 32 cols, 5 channels.
    for (int s = tid; s < STAGE * TILE; s += 256) {
        int r = s / TILE, c = s % TILE;
        float ax = 0.f, ay = 0.f, axx = 0.f, ayy = 0.f, axy = 0.f;
        #pragma unroll
        for (int j = 0; j < KW; ++j) {
            float xv = sx[r][c + j];
            float yv = sy[r][c + j];
            float wj = g[j];
            ax  += wj * xv;
            ay  += wj * yv;
            axx += wj * xv * xv;
            ayy += wj * yv * yv;
            axy += wj * xv * yv;
        }
        hx[r][c] = ax;  hy[r][c] = ay;
        hxx[r][c] = axx; hyy[r][c] = ayy; hxy[r][c] = axy;
    }
    __syncthreads();

    // Vertical pass + SSIM map; 4 outputs per thread.
    float acc = 0.f;
    #pragma unroll
    for (int k = 0; k < 4; ++k) {
        int s = tid + k * 256;
        int r = s / TILE, c = s % TILE;
        int oy = gy0 + r, ox = gx0 + c;
        if (oy < OUT_H && ox < OUT_W) {
            float mx = 0.f, my = 0.f, exx = 0.f, eyy = 0.f, exy = 0.f;
            #pragma unroll
            for (int j = 0; j < KW; ++j) {
                float wj = g[j];
                mx  += wj * hx[r + j][c];
                my  += wj * hy[r + j][c];
                exx += wj * hxx[r + j][c];
                eyy += wj * hyy[r + j][c];
                exy += wj * hxy[r + j][c];
            }
            float mxy = mx * my;
            float l  = (2.f * mxy + C1) / (mx * mx + my * my + C1);
            float cs = (2.f * (exy - mxy) + C2)
                     / ((exx - mx * mx) + (eyy - my * my) + C2);
            acc += l * cs;
        }
    }

    // Block reduction: wave shuffle then 4 partials through LDS.
    #pragma unroll
    for (int off = 32; off > 0; off >>= 1)
        acc += __shfl_down(acc, off, 64);
    int lane = tid & 63, wv = tid >> 6;
    if (lane == 0) red[wv] = acc;
    __syncthreads();
    if (tid == 0) {
        float t = red[0] + red[1] + red[2] + red[3];
        partial[(blockIdx.z * gridDim.y + blockIdx.y) * gridDim.x + blockIdx.x] = t;
    }
}

// Deterministic final reduction: fixed traversal order, double accumulation.
__global__ __launch_bounds__(256) void ssim_final(
    const float* __restrict__ partial, int n, float* __restrict__ out)
{
    __shared__ double red[256];
    double s = 0.0;
    for (int i = threadIdx.x; i < n; i += 256) s += (double)partial[i];
    red[threadIdx.x] = s;
    __syncthreads();
    for (int off = 128; off > 0; off >>= 1) {
        if (threadIdx.x < off) red[threadIdx.x] += red[threadIdx.x + off];
        __syncthreads();
    }
    if (threadIdx.x == 0) out[0] = (float)(1.0 - red[0] / (double)NPLANE);
}

extern "C" void kernel_launch(void* const* d_in, const int* in_sizes, int n_in,
                              void* d_out, int out_size, void* d_ws, size_t ws_size,
                              hipStream_t stream) {
    const float* in  = (const float*)d_in[0];
    const float* tgt = (const float*)d_in[1];
    const float* w   = (const float*)d_in[2];
    float* out = (float*)d_out;
    float* part = (float*)d_ws;

    dim3 grid(16, 16, NPLANE);   // ceil(502/32)=16 tiles per dim, 48 planes
    ssim_tile<<<grid, 256, 0, stream>>>(in, tgt, w, part);
    ssim_final<<<1, 256, 0, stream>>>(part, 16 * 16 * NPLANE, out);
}

// Round 2
// 116.008 us; speedup vs baseline: 1.2297x; 1.2297x over previous
//
#include <hip/hip_runtime.h>

#define KW 11
#define IMG 512
#define OUT_N 502
#define TILE 32
#define STAGE 42            // TILE + KW - 1
#define SP 43               // sst pitch (float4 units, odd -> banks spread by 3r)
#define HP 33               // hst pitch (float4 units, odd -> write spread by r)
#define NPLANE 48
#define C1 0.0001f
#define C2 0.0004f

// One block = one 32x32 output tile of one (b,c) plane. grid=(16,16,48), 256 thr.
__global__ __launch_bounds__(256) void ssim_tile(
    const float* __restrict__ in, const float* __restrict__ tgt,
    const float* __restrict__ w, float* __restrict__ partial)
{
    __shared__ float4 sst[STAGE][SP];   // staged (x, y, (x+y)^2, (x-y)^2)
    __shared__ float4 hst[STAGE][HP];   // H-blurred 4-tuple
    __shared__ float g1s[16];
    __shared__ float red[4];

    const int tid = threadIdx.x;
    const int gx0 = blockIdx.x * TILE;
    const int gy0 = blockIdx.y * TILE;
    const float* ip = in  + (size_t)blockIdx.z * (IMG * IMG);
    const float* tp = tgt + (size_t)blockIdx.z * (IMG * IMG);

    // 1D factor = row sums of the 2D kernel (exact: w2d = outer(g,g), sum g = 1).
    if (tid < KW) {
        float s = 0.f;
        #pragma unroll
        for (int j = 0; j < KW; ++j) s += w[tid * KW + j];
        g1s[tid] = s;
    }

    // Stage 42x42: one float4 per pixel.
    for (int s = tid; s < STAGE * STAGE; s += 256) {
        int r = s / STAGE, c = s - r * STAGE;
        int gy = gy0 + r, gx = gx0 + c;
        float xv = 0.f, yv = 0.f;
        if (gy < IMG && gx < IMG) {
            xv = ip[gy * IMG + gx];
            yv = tp[gy * IMG + gx];
        }
        float p = (xv + yv) * (xv + yv);
        float m = (xv - yv) * (xv - yv);
        sst[r][c] = make_float4(xv, yv, p, m);
    }
    __syncthreads();

    float g[KW];
    #pragma unroll
    for (int j = 0; j < KW; ++j) g[j] = g1s[j];

    // Horizontal pass: thread = (row, col-quad). 4 outputs/thread, 14 reads.
    {
        const int q4 = (tid >> 5) << 2;      // quad base col: 0,4,...,28
        const int rr = tid & 31;
        for (int rb = 0; rb < STAGE; rb += 32) {
            int r = rb + rr;
            if (r < STAGE) {
                float a0x=0,a0y=0,a0p=0,a0m=0, a1x=0,a1y=0,a1p=0,a1m=0;
                float a2x=0,a2y=0,a2p=0,a2m=0, a3x=0,a3y=0,a3p=0,a3m=0;
                #pragma unroll
                for (int t = 0; t < TILE/8 + 10; ++t) { /* dummy to keep unroll hint simple */ break; }
                #pragma unroll
                for (int t = 0; t < 14; ++t) {
                    float4 v = sst[r][q4 + t];
                    if (t <= 10)           { float wj=g[t];   a0x+=wj*v.x; a0y+=wj*v.y; a0p+=wj*v.z; a0m+=wj*v.w; }
                    if (t >= 1 && t <= 11) { float wj=g[t-1]; a1x+=wj*v.x; a1y+=wj*v.y; a1p+=wj*v.z; a1m+=wj*v.w; }
                    if (t >= 2 && t <= 12) { float wj=g[t-2]; a2x+=wj*v.x; a2y+=wj*v.y; a2p+=wj*v.z; a2m+=wj*v.w; }
                    if (t >= 3)            { float wj=g[t-3]; a3x+=wj*v.x; a3y+=wj*v.y; a3p+=wj*v.z; a3m+=wj*v.w; }
                }
                hst[r][q4 + 0] = make_float4(a0x, a0y, a0p, a0m);
                hst[r][q4 + 1] = make_float4(a1x, a1y, a1p, a1m);
                hst[r][q4 + 2] = make_float4(a2x, a2y, a2p, a2m);
                hst[r][q4 + 3] = make_float4(a3x, a3y, a3p, a3m);
            }
        }
    }
    __syncthreads();

    // Vertical pass + SSIM map: thread = (col, 4-row group). 14 reads, 4 outputs.
    float accs = 0.f;
    {
        const int tx = tid & 31;
        const int r4 = (tid >> 5) << 2;      // row group base: 0,4,...,28
        float a0x=0,a0y=0,a0p=0,a0m=0, a1x=0,a1y=0,a1p=0,a1m=0;
        float a2x=0,a2y=0,a2p=0,a2m=0, a3x=0,a3y=0,a3p=0,a3m=0;
        #pragma unroll
        for (int t = 0; t < 14; ++t) {
            float4 v = hst[r4 + t][tx];
            if (t <= 10)           { float wj=g[t];   a0x+=wj*v.x; a0y+=wj*v.y; a0p+=wj*v.z; a0m+=wj*v.w; }
            if (t >= 1 && t <= 11) { float wj=g[t-1]; a1x+=wj*v.x; a1y+=wj*v.y; a1p+=wj*v.z; a1m+=wj*v.w; }
            if (t >= 2 && t <= 12) { float wj=g[t-2]; a2x+=wj*v.x; a2y+=wj*v.y; a2p+=wj*v.z; a2m+=wj*v.w; }
            if (t >= 3)            { float wj=g[t-3]; a3x+=wj*v.x; a3y+=wj*v.y; a3p+=wj*v.z; a3m+=wj*v.w; }
        }
        const int ox = gx0 + tx;
        #pragma unroll
        for (int o = 0; o < 4; ++o) {
            float mx = (o==0)?a0x:(o==1)?a1x:(o==2)?a2x:a3x;
            float my = (o==0)?a0y:(o==1)?a1y:(o==2)?a2y:a3y;
            float P  = (o==0)?a0p:(o==1)?a1p:(o==2)?a2p:a3p;
            float M  = (o==0)?a0m:(o==1)?a1m:(o==2)?a2m:a3m;
            int oy = gy0 + r4 + o;
            if (oy < OUT_N && ox < OUT_N) {
                float A = mx * mx, B = my * my, mxy = mx * my;
                float sumsq = 0.5f * (P + M) - A - B;        // sigx2 + sigy2
                float sxy   = 0.25f * (P - M) - mxy;         // sigxy
                float num = (2.f * mxy + C1) * (2.f * sxy + C2);
                float den = (A + B + C1) * (sumsq + C2);
                accs += num / den;
            }
        }
    }

    // Block reduction.
    #pragma unroll
    for (int off = 32; off > 0; off >>= 1)
        accs += __shfl_down(accs, off, 64);
    int lane = tid & 63, wv = tid >> 6;
    if (lane == 0) red[wv] = accs;
    __syncthreads();
    if (tid == 0) {
        float t = red[0] + red[1] + red[2] + red[3];
        partial[(blockIdx.z * gridDim.y + blockIdx.y) * gridDim.x + blockIdx.x] = t;
    }
}

// Deterministic final reduction: fixed traversal, double accumulation.
__global__ __launch_bounds__(256) void ssim_final(
    const float* __restrict__ partial, int n, float* __restrict__ out)
{
    __shared__ double red[256];
    double s = 0.0;
    for (int i = threadIdx.x; i < n; i += 256) s += (double)partial[i];
    red[threadIdx.x] = s;
    __syncthreads();
    for (int off = 128; off > 0; off >>= 1) {
        if (threadIdx.x < off) red[threadIdx.x] += red[threadIdx.x + off];
        __syncthreads();
    }
    if (threadIdx.x == 0) out[0] = (float)(1.0 - red[0] / (double)NPLANE);
}

extern "C" void kernel_launch(void* const* d_in, const int* in_sizes, int n_in,
                              void* d_out, int out_size, void* d_ws, size_t ws_size,
                              hipStream_t stream) {
    const float* in  = (const float*)d_in[0];
    const float* tgt = (const float*)d_in[1];
    const float* w   = (const float*)d_in[2];
    float* out = (float*)d_out;
    float* part = (float*)d_ws;

    dim3 grid(16, 16, NPLANE);
    ssim_tile<<<grid, 256, 0, stream>>>(in, tgt, w, part);
    ssim_final<<<1, 256, 0, stream>>>(part, 16 * 16 * NPLANE, out);
}

// Round 3
// 55.993 us; speedup vs baseline: 2.5477x; 2.0718x over previous
//
#include <hip/hip_runtime.h>

#define IMG 512
#define OUT_N 502
#define NPLANE 48
#define STRIPS 16
#define C1c 0.0001f
#define C2c 0.0004f
#define EV_OFF 264   // odd-column sub-block offset (float4 units) in row buffer

__device__ __forceinline__ float ssim_px(float mx, float my, float P, float M) {
    float A = mx*mx, B = my*my, mxy = mx*my;
    float sumsq = 0.5f*(P+M) - A - B;      // sigx2 + sigy2
    float sxy   = 0.25f*(P-M) - mxy;       // sigxy
    float num = (2.f*mxy + C1c) * (2.f*sxy + C2c);
    float den = (A + B + C1c) * (sumsq + C2c);
    return num / den;
}

// Block = full-width 512-col strip, 32 output rows. V-blur in register ring
// (12 slots, static idx), H-blur via LDS row buffer (parity-split layout).
__global__ __launch_bounds__(256, 3) void ssim_strip(
    const float* __restrict__ in, const float* __restrict__ tgt,
    const float* __restrict__ w, float* __restrict__ partial)
{
    __shared__ float4 buf[2][528];
    __shared__ float g1s[16];
    __shared__ float red[4];

    const int tid   = threadIdx.x;
    const int strip = blockIdx.x;
    const int plane = blockIdx.y;
    const int r0 = strip * 32;
    const float* __restrict__ ip = in  + (size_t)plane * (IMG*IMG);
    const float* __restrict__ tp = tgt + (size_t)plane * (IMG*IMG);

    // 1D factor = row sums of 2D kernel (exact: w2d = outer(g,g), sum g = 1)
    if (tid < 11) {
        float s = 0.f;
        #pragma unroll
        for (int j = 0; j < 11; ++j) s += w[tid*11 + j];
        g1s[tid] = s;
    }
    __syncthreads();
    float g[11];
    #pragma unroll
    for (int j = 0; j < 11; ++j)
        g[j] = __int_as_float(__builtin_amdgcn_readfirstlane(__float_as_int(g1s[j])));

    float4 rA[12], rB[12];     // V-ring: cols tid and tid+256
    float acc = 0.f;
    const int wrA = (tid >> 1) + (tid & 1) * EV_OFF;   // col tid
    const int wrB = wrA + 128;                          // col tid+256

#define SS_LOAD(KK) \
    float xa=0.f, ya=0.f, xb=0.f, yb=0.f; \
    { const int r_ = r0 + (KK); \
      if (r_ < IMG) { \
        const float* ipr = ip + r_ * IMG; \
        const float* tpr = tp + r_ * IMG; \
        xa = ipr[tid];       ya = tpr[tid]; \
        xb = ipr[tid + 256]; yb = tpr[tid + 256]; \
      } }

#define SS_HPH(KK, RP) \
    { const int oy_ = r0 + (KK) - 11; \
      if (oy_ < OUT_N) { \
        float A0=0.f,A1=0.f,A2=0.f,A3=0.f,B0=0.f,B1=0.f,B2=0.f,B3=0.f; \
        _Pragma("unroll") \
        for (int j = 0; j < 12; ++j) { \
          float4 v = buf[RP][tid + (j>>1) + (j&1)*EV_OFF]; \
          if (j <= 10) { float wj=g[j];   A0+=wj*v.x; A1+=wj*v.y; A2+=wj*v.z; A3+=wj*v.w; } \
          if (j >= 1)  { float wj=g[j-1]; B0+=wj*v.x; B1+=wj*v.y; B2+=wj*v.z; B3+=wj*v.w; } \
        } \
        const int c0_ = 2*tid; \
        if (c0_ < OUT_N)     acc += ssim_px(A0,A1,A2,A3); \
        if (c0_ + 1 < OUT_N) acc += ssim_px(B0,B1,B2,B3); \
      } }

#define SS_RING(SLOT) \
    { float sa_=xa+ya, da_=xa-ya; rA[SLOT] = make_float4(xa, ya, sa_*sa_, da_*da_); \
      float sb_=xb+yb, db_=xb-yb; rB[SLOT] = make_float4(xb, yb, sb_*sb_, db_*db_); }

#define SS_VWR(SLOT, WP) \
    { float4 va_ = make_float4(0.f,0.f,0.f,0.f); \
      float4 vb_ = make_float4(0.f,0.f,0.f,0.f); \
      _Pragma("unroll") \
      for (int i = 0; i < 11; ++i) { \
        const int sl_ = ((SLOT) + 2 + i) % 12;   /* rows KK-10 .. KK */ \
        float wj = g[i]; \
        va_.x += wj*rA[sl_].x; va_.y += wj*rA[sl_].y; va_.z += wj*rA[sl_].z; va_.w += wj*rA[sl_].w; \
        vb_.x += wj*rB[sl_].x; vb_.y += wj*rB[sl_].y; vb_.z += wj*rB[sl_].z; vb_.w += wj*rB[sl_].w; \
      } \
      buf[WP][wrA] = va_; buf[WP][wrB] = vb_; }

#define SS_ITER(KK, SLOT, HEN, VEN) \
    { SS_LOAD(KK); \
      if (HEN) SS_HPH(KK, (((KK)&1)^1)); \
      SS_RING(SLOT); \
      if (VEN) SS_VWR(SLOT, ((KK)&1)); \
      if ((HEN) || (VEN)) __syncthreads(); }

    // k = 0..9: load + ring fill only (no LDS, no barrier)
    SS_ITER(0,0,0,0)  SS_ITER(1,1,0,0)  SS_ITER(2,2,0,0)  SS_ITER(3,3,0,0)
    SS_ITER(4,4,0,0)  SS_ITER(5,5,0,0)  SS_ITER(6,6,0,0)  SS_ITER(7,7,0,0)
    SS_ITER(8,8,0,0)  SS_ITER(9,9,0,0)
    // k = 10: first V write; k = 11: first H (out row 0)
    SS_ITER(10,10,0,1)
    SS_ITER(11,11,1,1)
    // k = 12..35: two macro-iterations of a static-12 body (I$-friendly)
    for (int kb = 12; kb <= 24; kb += 12) {
        SS_ITER(kb+0,0,1,1)   SS_ITER(kb+1,1,1,1)   SS_ITER(kb+2,2,1,1)
        SS_ITER(kb+3,3,1,1)   SS_ITER(kb+4,4,1,1)   SS_ITER(kb+5,5,1,1)
        SS_ITER(kb+6,6,1,1)   SS_ITER(kb+7,7,1,1)   SS_ITER(kb+8,8,1,1)
        SS_ITER(kb+9,9,1,1)   SS_ITER(kb+10,10,1,1) SS_ITER(kb+11,11,1,1)
    }
    // k = 36..41 (36 % 12 == 0 -> slots restart at 0, parity static)
    SS_ITER(36,0,1,1) SS_ITER(37,1,1,1) SS_ITER(38,2,1,1)
    SS_ITER(39,3,1,1) SS_ITER(40,4,1,1) SS_ITER(41,5,1,1)
    // tail: H for out row 31 (vb written at k=41 -> buf[1])
    SS_HPH(42, 1)

    // block reduction
    #pragma unroll
    for (int off = 32; off > 0; off >>= 1)
        acc += __shfl_down(acc, off, 64);
    const int lane = tid & 63, wv = tid >> 6;
    if (lane == 0) red[wv] = acc;
    __syncthreads();
    if (tid == 0)
        partial[plane * STRIPS + strip] = red[0] + red[1] + red[2] + red[3];
}

// Deterministic final reduction: fixed traversal, double accumulation.
__global__ __launch_bounds__(256) void ssim_final(
    const float* __restrict__ partial, int n, float* __restrict__ out)
{
    __shared__ double red[256];
    double s = 0.0;
    for (int i = threadIdx.x; i < n; i += 256) s += (double)partial[i];
    red[threadIdx.x] = s;
    __syncthreads();
    for (int off = 128; off > 0; off >>= 1) {
        if (threadIdx.x < off) red[threadIdx.x] += red[threadIdx.x + off];
        __syncthreads();
    }
    if (threadIdx.x == 0) out[0] = (float)(1.0 - red[0] / (double)NPLANE);
}

extern "C" void kernel_launch(void* const* d_in, const int* in_sizes, int n_in,
                              void* d_out, int out_size, void* d_ws, size_t ws_size,
                              hipStream_t stream) {
    const float* in  = (const float*)d_in[0];
    const float* tgt = (const float*)d_in[1];
    const float* wt  = (const float*)d_in[2];
    float* out  = (float*)d_out;
    float* part = (float*)d_ws;

    dim3 grid(STRIPS, NPLANE);   // 16 row-strips x 48 planes = 768 blocks = 3/CU
    ssim_strip<<<grid, 256, 0, stream>>>(in, tgt, wt, part);
    ssim_final<<<1, 256, 0, stream>>>(part, STRIPS * NPLANE, out);
}